// Round 1
// baseline (344.234 us; speedup 1.0000x reference)
//
#include <hip/hip_runtime.h>

// CRF forward-algorithm loss: B=1024 sequences, T=1024 steps, L=32 states.
// loss = mean_b( logsumexp(alpha_T) - gold_score ),
// alpha recurrence: alpha_t[i] = lse_j(trans[i,j] + alpha_{t-1}[j]) + feat[t,i]
//
// Strategy: real-space matvec with hoisted E = exp(trans):
//   P[i] = sum_j E[i,j] * exp(alpha[j] - base),  alpha'[i] = base + ln P[i] + feat
// base = alpha[1] (always near max; state 0 = START is the only -1e4 row).
// 2 sequences per wave (32-lane groups); bpermute broadcasts within groups.

constexpr int BN = 1024;
constexpr int TN = 1024;
constexpr int LN = 32;

__device__ __forceinline__ float bcast32(float v, int srcInGroup, int bbase) {
    int r = __builtin_amdgcn_ds_bpermute(bbase + (srcInGroup << 2), __float_as_int(v));
    return __int_as_float(r);
}

__global__ __launch_bounds__(64) void crf_fwd(
    const float* __restrict__ features,     // [B][T][L]
    const float* __restrict__ transitions,  // [L][L]
    const int*   __restrict__ labels,       // [B][T]
    float* __restrict__ out)                // [1]
{
    const int lane = threadIdx.x & 63;
    const int i    = lane & 31;             // state index within group
    const int grp  = lane >> 5;             // which sequence half of the wave
    const int seq  = blockIdx.x * 2 + grp;
    const int bbase = (lane & 32) << 2;     // byte base of this group's lane 0 for bpermute

    const float* __restrict__ feat = features + (size_t)seq * TN * LN;
    const int*   __restrict__ lab  = labels   + (size_t)seq * TN;

    // Loop-invariant: E[j] = exp(trans[i][j]) for this lane's state row i.
    float E[32];
    #pragma unroll
    for (int j = 0; j < 32; ++j)
        E[j] = __expf(transitions[i * LN + j]);

    // ---- t = 1 (exact: alpha0 is a delta on START=0, so alpha1[i] = trans[i,0] + feat[1,i]) ----
    float f     = feat[LN + i];
    float alpha = transitions[i * LN + 0] + f;
    int   prev  = lab[0];
    int   cur   = lab[1];
    float gold  = transitions[cur * LN + prev] + bcast32(f, cur, bbase);

    // Prefetch state for t = 2
    float f2  = feat[2 * LN + i];
    int   c2  = lab[2];
    float gt  = transitions[c2 * LN + cur];   // trans[cur_2, prev_2=lab[1]]
    cur = c2;
    f   = f2;

    // ---- main scan: t = 2 .. T-1 ----
    for (int t = 2; t < TN; ++t) {
        // prefetch loads for t+1 (clamped on last iter; results discarded)
        const int nt = (t + 1 < TN) ? (t + 1) : (TN - 1);
        float fn = feat[nt * LN + i];
        int   cn = lab[nt];

        // alpha update for time t
        float base = bcast32(alpha, 1, bbase);
        float e    = __expf(alpha - base);

        float a0 = 0.f, a1 = 0.f, a2 = 0.f, a3 = 0.f;
        #pragma unroll
        for (int j = 0; j < 32; j += 4) {
            a0 = fmaf(E[j + 0], bcast32(e, j + 0, bbase), a0);
            a1 = fmaf(E[j + 1], bcast32(e, j + 1, bbase), a1);
            a2 = fmaf(E[j + 2], bcast32(e, j + 2, bbase), a2);
            a3 = fmaf(E[j + 3], bcast32(e, j + 3, bbase), a3);
        }
        float P = (a0 + a1) + (a2 + a3);
        P = fmaxf(P, 1e-37f);                         // state 0 (START row) underflows; keep finite
        alpha = fmaf(0.69314718f, __log2f(P), base) + f;

        // gold contribution for time t (gt prefetched last iter)
        gold += gt + bcast32(f, cur, bbase);

        // prefetch gold-transition for t+1: trans[lab[t+1], lab[t]]
        gt  = transitions[cn * LN + cur];
        cur = cn;
        f   = fn;
    }

    // ---- forward score: logsumexp over the 32 states of this group ----
    float m = alpha;
    #pragma unroll
    for (int s = 16; s; s >>= 1) m = fmaxf(m, __shfl_xor(m, s, 32));
    float es = __expf(alpha - m);
    #pragma unroll
    for (int s = 16; s; s >>= 1) es += __shfl_xor(es, s, 32);
    float fs = m + 0.69314718f * __log2f(es);

    if (i == 0) atomicAdd(out, (fs - gold) * (1.0f / (float)BN));
}

extern "C" void kernel_launch(void* const* d_in, const int* in_sizes, int n_in,
                              void* d_out, int out_size, void* d_ws, size_t ws_size,
                              hipStream_t stream) {
    const float* features    = (const float*)d_in[0];
    const float* transitions = (const float*)d_in[1];
    const int*   labels      = (const int*)d_in[2];
    float* out = (float*)d_out;

    // Output accumulated via atomicAdd; zero it inside the captured stream so
    // graph replays are self-initializing.
    hipMemsetAsync(out, 0, sizeof(float), stream);
    crf_fwd<<<dim3(BN / 2), dim3(64), 0, stream>>>(features, transitions, labels, out);
}

// Round 2
// 282.812 us; speedup vs baseline: 1.2172x; 1.2172x over previous
//
#include <hip/hip_runtime.h>
#include <hip/hip_bf16.h>

// CRF loss via associative chunked scan.
// Phase 1: each wave computes one chunk's 32x32 transfer-matrix product
//   P_c = prod_t exp(trans + feat_t[row] - K)  (real space, bf16 MFMA,
//   per-column pow2 rescale every 4 steps), writes log(P_c) to ws.
//   Also accumulates the gold-path score for its chunk (fused).
// Phase 2: per sequence, exact log-space matvec over CH chunk matrices,
//   final logsumexp, atomicAdd into out.

constexpr int BN = 1024, TN = 1024, LN = 32;
constexpr float KSHIFT = 8.5f;     // makes per-step factors ~e^{-2}: monotone decay
constexpr float LN2F   = 0.69314718056f;

typedef __attribute__((ext_vector_type(8)))  short bf16x8;
typedef __attribute__((ext_vector_type(16))) float f32x16;

static __device__ __forceinline__ unsigned pkbf(float a, float b) {
    __hip_bfloat16 ha = __float2bfloat16(a), hb = __float2bfloat16(b);
    unsigned short sa, sb;
    __builtin_memcpy(&sa, &ha, 2); __builtin_memcpy(&sb, &hb, 2);
    return (unsigned)sa | ((unsigned)sb << 16);
}
static __device__ __forceinline__ float bpermf(float v, int srcLane) {
    int r = __builtin_amdgcn_ds_bpermute(srcLane << 2, __float_as_int(v));
    return __int_as_float(r);
}
static __device__ __forceinline__ int bpermi(int v, int srcLane) {
    return __builtin_amdgcn_ds_bpermute(srcLane << 2, v);
}

// ---------------- Phase 1: chunk transfer-matrix products ----------------
__global__ __launch_bounds__(256) void crf_chunk(
    const float* __restrict__ feat,   // [B][T][L]
    const float* __restrict__ trans,  // [L][L]
    const int*   __restrict__ lab,    // [B][T]
    float* __restrict__ ws,           // [B*CH][32][32] log-space products
    float* __restrict__ out,          // [1] (gold subtracted here)
    int CHS)
{
    const int CH = 1 << CHS, LEN = TN >> CHS;
    const int l = threadIdx.x & 63, n = l & 31, h = l >> 5;
    const int gid = blockIdx.x * 4 + (threadIdx.x >> 6);  // wave id = chunk id
    const int c = gid & (CH - 1), b = gid >> CHS;

    const float* __restrict__ fb = feat + (size_t)b * TN * LN;
    const int*   __restrict__ lb = lab  + (size_t)b * TN;

    // A-operand constants: E[e] = exp(trans[n][k(e)] - K).
    // A layout (32x32x16): lane l -> row m = l&31, k = 8*(l>>5) + e.
    float E[16];
    #pragma unroll
    for (int e = 0; e < 8; ++e) E[e]     = __expf(trans[n * LN + 8 * h + e]      - KSHIFT);
    #pragma unroll
    for (int e = 0; e < 8; ++e) E[8 + e] = __expf(trans[n * LN + 16 + 8 * h + e] - KSHIFT);

    // Running product as next-step B operand; init = Identity.
    // B layout (32x32x16): lane l -> col n = l&31, k = 8*(l>>5) + e.
    union BU { bf16x8 v; unsigned u[4]; } B1f, B2f;
    #pragma unroll
    for (int r = 0; r < 4; ++r) {
        int k0 = 8 * h + 2 * r, k1 = k0 + 1;
        B1f.u[r] = (k0 == n ? 0x3F80u : 0u) | ((k1 == n ? 0x3F80u : 0u) << 16);
        B2f.u[r] = (k0 + 16 == n ? 0x3F80u : 0u) | ((k1 + 16 == n ? 0x3F80u : 0u) << 16);
    }

    const int start = c * LEN, te = start + LEN;
    const int tm = (c == 0) ? 2 : start;   // chunk 0 starts at t=2 (t=1 folded into alpha_1)

    float gold = 0.f;
    int pv;
    if (c == 0) {
        int c0 = lb[1];
        float f1 = fb[LN + n];
        gold = trans[c0 * LN + lb[0]] + bpermf(f1, c0);
        pv = c0;
    } else {
        pv = lb[start - 1];
    }

    float fcur = fb[(size_t)tm * LN + n];
    int   ct   = lb[tm];
    int   sc   = 0;          // accumulated per-column pow2 exponent (consistent in both halves)
    f32x16 C;
    #pragma unroll
    for (int i = 0; i < 16; ++i) C[i] = 0.f;

    for (int t = tm; t < te; ++t) {
        // prefetch t+1
        const int tn2 = (t + 1 < te) ? (t + 1) : t;
        float fnx = fb[(size_t)tn2 * LN + n];
        int   cnx = lb[tn2];

        // gold (off critical path)
        gold += trans[ct * LN + pv] + bpermf(fcur, ct);
        pv = ct;

        // A = exp(trans + feat_t[row] - K): row factor F is lane-constant
        float F = __expf(fcur);
        union BU A1, A2;
        #pragma unroll
        for (int r = 0; r < 4; ++r) {
            A1.u[r] = pkbf(E[2 * r] * F,     E[2 * r + 1] * F);
            A2.u[r] = pkbf(E[8 + 2 * r] * F, E[9 + 2 * r] * F);
        }

        f32x16 Z;
        #pragma unroll
        for (int i = 0; i < 16; ++i) Z[i] = 0.f;
        C = __builtin_amdgcn_mfma_f32_32x32x16_bf16(A1.v, B1f.v, Z, 0, 0, 0);
        C = __builtin_amdgcn_mfma_f32_32x32x16_bf16(A2.v, B2f.v, C, 0, 0, 0);

        // per-column pow2 rescale every 4 steps (exact; diag commutes right)
        if ((t & 3) == 3) {
            float cm = C[0];
            #pragma unroll
            for (int i = 1; i < 16; ++i) cm = fmaxf(cm, C[i]);
            cm = fmaxf(cm, bpermf(cm, l ^ 32));   // column consensus across lane halves
            cm = fmaxf(cm, 1e-30f);
            int ex; frexpf(cm, &ex);
            sc += ex;
            #pragma unroll
            for (int i = 0; i < 16; ++i) C[i] = ldexpf(C[i], -ex);
        }

        // C (col=lane&31, row=(r&3)+8*(r>>2)+4*h) -> B operands for next step
        unsigned PK[8], PP[8];
        #pragma unroll
        for (int r = 0; r < 8; ++r) PK[r] = pkbf(C[2 * r], C[2 * r + 1]);
        #pragma unroll
        for (int r = 0; r < 8; ++r) PP[r] = (unsigned)bpermi((int)PK[r], l ^ 32);
        const bool lo = (l < 32);
        B1f.u[0] = lo ? PK[0] : PP[2];
        B1f.u[1] = lo ? PK[1] : PP[3];
        B1f.u[2] = lo ? PP[0] : PK[2];
        B1f.u[3] = lo ? PP[1] : PK[3];
        B2f.u[0] = lo ? PK[4] : PP[6];
        B2f.u[1] = lo ? PK[5] : PP[7];
        B2f.u[2] = lo ? PP[4] : PK[6];
        B2f.u[3] = lo ? PP[5] : PK[7];

        fcur = fnx; ct = cnx;
    }

    if (l == 0) atomicAdd(out, -gold * (1.0f / (float)BN));

    // write log-space chunk matrix: log(true) = ln(C) + sc*ln2 + K*len
    const float add = KSHIFT * (float)(te - tm) + (float)sc * LN2F;
    float* __restrict__ w = ws + ((size_t)gid << 10);
    #pragma unroll
    for (int r = 0; r < 16; ++r) {
        int row = (r & 3) + 8 * (r >> 2) + 4 * h;
        float v = C[r];
        w[row * LN + n] = (v > 0.f) ? (__logf(v) + add) : -10000.0f;
    }
}

// ---------------- Phase 2: log-space combine + final lse ----------------
__global__ __launch_bounds__(64) void crf_combine(
    const float* __restrict__ trans,
    const float* __restrict__ feat,
    const float* __restrict__ ws,
    float* __restrict__ out,
    int CHS)
{
    const int CH = 1 << CHS;
    const int l = threadIdx.x & 63, i = l & 31;
    const int seq = blockIdx.x * 2 + (l >> 5);
    const int bb = (l & 32) << 2;   // group-local bpermute base

    // alpha_1[i] = trans[i][0] + feat[1][i]  (exact)
    float alpha = trans[i * LN] + feat[(size_t)seq * TN * LN + LN + i];
    const float* __restrict__ wsb = ws + ((size_t)seq << (10 + CHS));

    for (int c = 0; c < CH; ++c) {
        const float4* Mr = (const float4*)(wsb + (c << 10) + i * LN);
        float vv[32];
        #pragma unroll
        for (int q = 0; q < 8; ++q) {
            float4 m4 = Mr[q];
            vv[4 * q + 0] = m4.x; vv[4 * q + 1] = m4.y;
            vv[4 * q + 2] = m4.z; vv[4 * q + 3] = m4.w;
        }
        float mx = -1e30f;
        #pragma unroll
        for (int j = 0; j < 32; ++j) {
            int r = __builtin_amdgcn_ds_bpermute(bb + (j << 2), __float_as_int(alpha));
            vv[j] += __int_as_float(r);
            mx = fmaxf(mx, vv[j]);
        }
        float s = 0.f;
        #pragma unroll
        for (int j = 0; j < 32; ++j) s += __expf(vv[j] - mx);
        alpha = mx + __logf(s);
    }

    // forward score = lse over 32 states
    float m = alpha;
    #pragma unroll
    for (int s = 16; s; s >>= 1) m = fmaxf(m, __shfl_xor(m, s, 32));
    float es = __expf(alpha - m);
    #pragma unroll
    for (int s = 16; s; s >>= 1) es += __shfl_xor(es, s, 32);
    float fs = m + __logf(es);

    if (i == 0) atomicAdd(out, fs * (1.0f / (float)BN));
}

extern "C" void kernel_launch(void* const* d_in, const int* in_sizes, int n_in,
                              void* d_out, int out_size, void* d_ws, size_t ws_size,
                              hipStream_t stream) {
    const float* features    = (const float*)d_in[0];
    const float* transitions = (const float*)d_in[1];
    const int*   labels      = (const int*)d_in[2];
    float* out = (float*)d_out;
    float* ws  = (float*)d_ws;

    // pick largest CH in {8,4,2,1} whose chunk-matrix scratch fits ws
    int CHS = 3;
    while (CHS > 0 && ws_size < (((size_t)BN << CHS) * (LN * LN * 4))) --CHS;
    const int CH = 1 << CHS;

    hipMemsetAsync(out, 0, sizeof(float), stream);
    crf_chunk<<<dim3((BN * CH) / 4), dim3(256), 0, stream>>>(
        features, transitions, labels, ws, out, CHS);
    crf_combine<<<dim3(BN / 2), dim3(64), 0, stream>>>(
        transitions, features, ws, out, CHS);
}

// Round 3
// 177.423 us; speedup vs baseline: 1.9402x; 1.5940x over previous
//
#include <hip/hip_runtime.h>
#include <hip/hip_bf16.h>

// CRF loss via associative chunked scan (layouts verified in R2).
// R3: truncating v_perm bf16 packs (1 instr/pair), v_permlane32_swap repack
// (4 instrs, no DS), scalar gold path, rescale every 8 steps.

constexpr int BN = 1024, TN = 1024, LN = 32;
constexpr float KSHIFT = 8.5f;     // per-step factors ~e^{-2}: monotone decay
constexpr float LN2F   = 0.69314718056f;

typedef __attribute__((ext_vector_type(8)))  short bf16x8;
typedef __attribute__((ext_vector_type(16))) float f32x16;

// pack two f32 -> (bf16(a) | bf16(b)<<16) by truncation: one v_perm_b32
static __device__ __forceinline__ unsigned pktrunc(float a, float b) {
#if __has_builtin(__builtin_amdgcn_perm)
    return __builtin_amdgcn_perm(__float_as_uint(b), __float_as_uint(a), 0x07060302u);
#else
    return (__float_as_uint(a) >> 16) | (__float_as_uint(b) & 0xFFFF0000u);
#endif
}

// v_permlane32_swap_b32: a.row1 <-> b.row0.
// After: a = {a[l] (l<32), b[l-32] (l>=32)},  b = {a[l+32] (l<32), b[l] (l>=32)}
#define PLSWAP(a, b) asm("v_permlane32_swap_b32 %0, %1" : "+v"(a), "+v"(b))

// ---------------- Phase 1: chunk transfer-matrix products ----------------
__global__ __launch_bounds__(256) void crf_chunk(
    const float* __restrict__ feat,   // [B][T][L]
    const float* __restrict__ trans,  // [L][L]
    const int*   __restrict__ lab,    // [B][T]
    float* __restrict__ ws,           // [B*CH][32][32] log-space products
    float* __restrict__ out,          // [1] (gold subtracted here)
    int CHS)
{
    const int CH = 1 << CHS, LEN = TN >> CHS;
    const int l = threadIdx.x & 63, n = l & 31, h = l >> 5;
    const int wid = __builtin_amdgcn_readfirstlane((int)(threadIdx.x >> 6));
    const int gid = blockIdx.x * 4 + wid;            // wave id = chunk id
    const int c = gid & (CH - 1), b = gid >> CHS;

    const float* __restrict__ fb = feat + (size_t)b * TN * LN;
    const int*   __restrict__ lb = lab  + (size_t)b * TN;

    // A-operand constants: E[e] = exp(trans[n][k(e)] - K); lane -> row m=l&31, k=8h+e.
    float E[16];
    #pragma unroll
    for (int e = 0; e < 8; ++e) E[e]     = __expf(trans[n * LN + 8 * h + e]      - KSHIFT);
    #pragma unroll
    for (int e = 0; e < 8; ++e) E[8 + e] = __expf(trans[n * LN + 16 + 8 * h + e] - KSHIFT);

    // Running product as B operand (lane -> col n, k=8h+e); init Identity.
    union BU { bf16x8 v; unsigned u[4]; } B1f, B2f;
    #pragma unroll
    for (int r = 0; r < 4; ++r) {
        int k0 = 8 * h + 2 * r, k1 = k0 + 1;
        B1f.u[r] = (k0 == n ? 0x3F80u : 0u) | ((k1 == n ? 0x3F80u : 0u) << 16);
        B2f.u[r] = (k0 + 16 == n ? 0x3F80u : 0u) | ((k1 + 16 == n ? 0x3F80u : 0u) << 16);
    }

    const int start = c * LEN, te = start + LEN;
    const int tm = (c == 0) ? 2 : start;   // chunk 0: t=1 folded into alpha_1 (phase 2)

    // Gold path: all wave-uniform scalar loads (no bpermute).
    float gold = 0.f;
    if (c == 0) {
        int c0 = lb[1];
        gold = trans[c0 * LN + lb[0]] + fb[LN + c0];
    }
    int   ct = lb[tm];
    int   pv = lb[tm - 1];
    float gt = trans[ct * LN + pv];
    float gf = fb[(size_t)tm * LN + ct];

    float fcur = fb[(size_t)tm * LN + n];
    int   sc   = 0;                       // accumulated pow2 exponent (per column)
    f32x16 ZR;
    #pragma unroll
    for (int i = 0; i < 16; ++i) ZR[i] = 0.f;
    f32x16 C;

    for (int t = tm; t < te; ++t) {
        // ---- prefetch t+1 (clamped on last iter; those values are discarded)
        const int tn2 = (t + 1 < te) ? (t + 1) : t;
        float fnx = fb[(size_t)tn2 * LN + n];   // vector load
        int   cnx = lb[tn2];                    // scalar
        gold += gt + gf;                        // gold for step t (prefetched)
        gt = trans[cnx * LN + ct];              // scalar
        gf = fb[(size_t)tn2 * LN + cnx];        // scalar
        ct = cnx;

        // ---- A = exp(trans + feat_t[row] - K); row factor lane-constant
        float F = __expf(fcur);
        union BU A1, A2;
        #pragma unroll
        for (int r = 0; r < 4; ++r) {
            A1.u[r] = pktrunc(E[2 * r] * F,     E[2 * r + 1] * F);
            A2.u[r] = pktrunc(E[8 + 2 * r] * F, E[9 + 2 * r] * F);
        }

        C = __builtin_amdgcn_mfma_f32_32x32x16_bf16(A1.v, B1f.v, ZR, 0, 0, 0);
        C = __builtin_amdgcn_mfma_f32_32x32x16_bf16(A2.v, B2f.v, C, 0, 0, 0);

        // ---- per-column pow2 rescale every 8 steps (exact; diag commutes right)
        if ((t & 7) == 7) {
            float cm = C[0];
            #pragma unroll
            for (int i = 1; i < 16; ++i) cm = fmaxf(cm, C[i]);
            unsigned ca = __float_as_uint(cm), cb = ca;
            PLSWAP(ca, cb);                              // column consensus across halves
            cm = fmaxf(__uint_as_float(ca), __uint_as_float(cb));
            cm = fmaxf(cm, 1e-30f);
            int ex; frexpf(cm, &ex);
            sc += ex;
            #pragma unroll
            for (int i = 0; i < 16; ++i) C[i] = ldexpf(C[i], -ex);
        }

        // ---- C (col=l&31, row=(r&3)+8*(r>>2)+4h) -> next-step B operands
        unsigned PK[8];
        #pragma unroll
        for (int r = 0; r < 8; ++r) PK[r] = pktrunc(C[2 * r], C[2 * r + 1]);
        PLSWAP(PK[0], PK[2]);  PLSWAP(PK[1], PK[3]);
        PLSWAP(PK[4], PK[6]);  PLSWAP(PK[5], PK[7]);
        B1f.u[0] = PK[0]; B1f.u[1] = PK[1]; B1f.u[2] = PK[2]; B1f.u[3] = PK[3];
        B2f.u[0] = PK[4]; B2f.u[1] = PK[5]; B2f.u[2] = PK[6]; B2f.u[3] = PK[7];

        fcur = fnx;
    }

    if (l == 0) atomicAdd(out, -gold * (1.0f / (float)BN));

    // write log-space chunk matrix: log(true) = ln(C) + sc*ln2 + K*len
    const float add = KSHIFT * (float)(te - tm) + (float)sc * LN2F;
    float* __restrict__ w = ws + ((size_t)gid << 10);
    #pragma unroll
    for (int r = 0; r < 16; ++r) {
        int row = (r & 3) + 8 * (r >> 2) + 4 * h;
        float v = C[r];
        w[row * LN + n] = (v > 0.f) ? (__logf(v) + add) : -10000.0f;
    }
}

// ---------------- Phase 2: log-space combine + final lse ----------------
__global__ __launch_bounds__(64) void crf_combine(
    const float* __restrict__ trans,
    const float* __restrict__ feat,
    const float* __restrict__ ws,
    float* __restrict__ out,
    int CHS)
{
    const int CH = 1 << CHS;
    const int l = threadIdx.x & 63, i = l & 31;
    const int seq = blockIdx.x * 2 + (l >> 5);
    const int bb = (l & 32) << 2;   // group-local bpermute base

    // alpha_1[i] = trans[i][0] + feat[1][i]  (exact)
    float alpha = trans[i * LN] + feat[(size_t)seq * TN * LN + LN + i];
    const float* __restrict__ wsb = ws + ((size_t)seq << (10 + CHS));

    for (int c = 0; c < CH; ++c) {
        const float4* Mr = (const float4*)(wsb + (c << 10) + i * LN);
        float vv[32];
        #pragma unroll
        for (int q = 0; q < 8; ++q) {
            float4 m4 = Mr[q];
            vv[4 * q + 0] = m4.x; vv[4 * q + 1] = m4.y;
            vv[4 * q + 2] = m4.z; vv[4 * q + 3] = m4.w;
        }
        float mx = -1e30f;
        #pragma unroll
        for (int j = 0; j < 32; ++j) {
            int r = __builtin_amdgcn_ds_bpermute(bb + (j << 2), __float_as_int(alpha));
            vv[j] += __int_as_float(r);
            mx = fmaxf(mx, vv[j]);
        }
        float s = 0.f;
        #pragma unroll
        for (int j = 0; j < 32; ++j) s += __expf(vv[j] - mx);
        alpha = mx + __logf(s);
    }

    // forward score = lse over 32 states
    float m = alpha;
    #pragma unroll
    for (int s = 16; s; s >>= 1) m = fmaxf(m, __shfl_xor(m, s, 32));
    float es = __expf(alpha - m);
    #pragma unroll
    for (int s = 16; s; s >>= 1) es += __shfl_xor(es, s, 32);
    float fs = m + __logf(es);

    if (i == 0) atomicAdd(out, fs * (1.0f / (float)BN));
}

extern "C" void kernel_launch(void* const* d_in, const int* in_sizes, int n_in,
                              void* d_out, int out_size, void* d_ws, size_t ws_size,
                              hipStream_t stream) {
    const float* features    = (const float*)d_in[0];
    const float* transitions = (const float*)d_in[1];
    const int*   labels      = (const int*)d_in[2];
    float* out = (float*)d_out;
    float* ws  = (float*)d_ws;

    int CHS = 3;
    while (CHS > 0 && ws_size < (((size_t)BN << CHS) * (LN * LN * 4))) --CHS;
    const int CH = 1 << CHS;

    hipMemsetAsync(out, 0, sizeof(float), stream);
    crf_chunk<<<dim3((BN * CH) / 4), dim3(256), 0, stream>>>(
        features, transitions, labels, ws, out, CHS);
    crf_combine<<<dim3(BN / 2), dim3(64), 0, stream>>>(
        transitions, features, ws, out, CHS);
}